// Round 1
// baseline (230.554 us; speedup 1.0000x reference)
//
#include <hip/hip_runtime.h>

// ShiftVarConv2D: out[n,m,y,x] = sum_{di,dj} coded[n,y+di-1,x+dj-1] *
//                 W[(y%8)*8+(x%8), m, di*3+dj] + bias[g*16+m]
// N=128, H=128, SUB=16 out channels, 3x3 window, weights vary with (y%8,x%8).

#define H 128
#define N_BATCH 128
#define SUB 16

// Transpose weights+bias into [b1][m][80] : 72 weights (j*9+i) + 8 bias (j).
// Wt[(b1*16+m)*80 + j*9 + i] = w[((b1*8+j)*16+m)*9 + i]
// Wt[(b1*16+m)*80 + 72 + j] = bias[(b1*8+j)*16+m]
__global__ void wprep_kernel(const float* __restrict__ w,
                             const float* __restrict__ bias,
                             float* __restrict__ Wt) {
    int t = blockIdx.x * blockDim.x + threadIdx.x;   // 0..1023
    if (t >= 8 * 16 * 8) return;
    int b1 = t >> 7;          // 0..7
    int m  = (t >> 3) & 15;   // 0..15
    int j  = t & 7;           // 0..7
    int oc = (b1 * 8 + j) * 16 + m;
    float* dst = Wt + (b1 * 16 + m) * 80;
#pragma unroll
    for (int i = 0; i < 9; ++i) dst[j * 9 + i] = w[oc * 9 + i];
    dst[72 + j] = bias[oc];
}

__global__ __launch_bounds__(256) void shiftconv_kernel(
        const float* __restrict__ x,
        const float* __restrict__ Wt,
        float* __restrict__ out) {
    // blockIdx.x in [0,1024): n = /8, b1 = %8  (b1 is wave-uniform -> scalar weight loads)
    int n  = blockIdx.x >> 3;
    int b1 = blockIdx.x & 7;
    int c  = threadIdx.x & 15;   // x-chunk: handles x = 8c..8c+7 (all b2)
    int rr = threadIdx.x >> 4;   // 0..15 -> row y = b1 + 8*rr
    int y  = b1 + (rr << 3);
    int x0 = c << 3;

    const float* xn = x + (size_t)n * (H * H);

    // Load 3 rows x 10 values: in[dy][k] = coded[n, y+dy-1, x0+k-1] (0-padded)
    float in[3][10];
#pragma unroll
    for (int dy = 0; dy < 3; ++dy) {
        int ry = y + dy - 1;
        if (ry >= 0 && ry < H) {
            const float* row = xn + ry * H + x0;
            float4 a = *(const float4*)(row);
            float4 b = *(const float4*)(row + 4);
            in[dy][1] = a.x; in[dy][2] = a.y; in[dy][3] = a.z; in[dy][4] = a.w;
            in[dy][5] = b.x; in[dy][6] = b.y; in[dy][7] = b.z; in[dy][8] = b.w;
            in[dy][0] = (x0 > 0)     ? row[-1] : 0.0f;
            in[dy][9] = (x0 + 8 < H) ? row[8]  : 0.0f;
        } else {
#pragma unroll
            for (int k = 0; k < 10; ++k) in[dy][k] = 0.0f;
        }
    }

    float* outbase = out + ((size_t)(n * SUB) * (H * H)) + y * H + x0;
    const float* wb = Wt + b1 * (16 * 80);

    for (int m = 0; m < SUB; ++m) {
        const float* wp = wb + m * 80;   // uniform address -> s_load
        float acc[8];
#pragma unroll
        for (int j = 0; j < 8; ++j) acc[j] = wp[72 + j];   // bias
#pragma unroll
        for (int dy = 0; dy < 3; ++dy) {
#pragma unroll
            for (int dj = 0; dj < 3; ++dj) {
#pragma unroll
                for (int j = 0; j < 8; ++j) {
                    acc[j] = fmaf(in[dy][j + dj], wp[j * 9 + dy * 3 + dj], acc[j]);
                }
            }
        }
        float* op = outbase + (size_t)m * (H * H);
        *(float4*)(op)     = make_float4(acc[0], acc[1], acc[2], acc[3]);
        *(float4*)(op + 4) = make_float4(acc[4], acc[5], acc[6], acc[7]);
    }
}

extern "C" void kernel_launch(void* const* d_in, const int* in_sizes, int n_in,
                              void* d_out, int out_size, void* d_ws, size_t ws_size,
                              hipStream_t stream) {
    const float* coded  = (const float*)d_in[0];
    const float* weight = (const float*)d_in[1];
    const float* bias   = (const float*)d_in[2];
    float* out = (float*)d_out;
    float* Wt  = (float*)d_ws;   // needs 8*16*80*4 = 40960 bytes

    wprep_kernel<<<4, 256, 0, stream>>>(weight, bias, Wt);
    shiftconv_kernel<<<N_BATCH * 8, 256, 0, stream>>>(coded, Wt, out);
}

// Round 2
// 199.818 us; speedup vs baseline: 1.1538x; 1.1538x over previous
//
#include <hip/hip_runtime.h>

// ShiftVarConv2D: out[n,m,y,x] = sum_{di,dj} coded[n,y+di-1,x+dj-1] *
//                 W[(y%8)*8+(x%8), m, di*3+dj] + bias[g*16+m]
// N=128, H=128, SUB=16 out channels, 3x3 window, weights vary with (y%8,x%8).

#define H 128
#define N_BATCH 128
#define SUB 16

// Transpose weights+bias into [b1][m][80] : 72 weights (j*9+i) + 8 bias (j).
// Wt[(b1*16+m)*80 + j*9 + i] = w[((b1*8+j)*16+m)*9 + i]
// Wt[(b1*16+m)*80 + 72 + j] = bias[(b1*8+j)*16+m]
__global__ void wprep_kernel(const float* __restrict__ w,
                             const float* __restrict__ bias,
                             float* __restrict__ Wt) {
    int t = blockIdx.x * blockDim.x + threadIdx.x;   // 0..1023
    if (t >= 8 * 16 * 8) return;
    int b1 = t >> 7;          // 0..7
    int m  = (t >> 3) & 15;   // 0..15
    int j  = t & 7;           // 0..7
    int oc = (b1 * 8 + j) * 16 + m;
    float* dst = Wt + (b1 * 16 + m) * 80;
#pragma unroll
    for (int i = 0; i < 9; ++i) dst[j * 9 + i] = w[oc * 9 + i];
    dst[72 + j] = bias[oc];
}

// grid = 128 n * 8 b1 * 2 mh = 2048 blocks; block = 256 threads.
// Each block: fixed (n, b1, m-half). Thread (c=t&15, rr=t>>4) computes
// row y = b1+8*rr, x = 8c..8c+7, for 8 m values.
__global__ __launch_bounds__(256, 6) void shiftconv_kernel(
        const float* __restrict__ x,
        const float* __restrict__ Wt,
        float* __restrict__ out) {
    int bid = blockIdx.x;
    int n   = bid >> 4;
    int b1  = (bid >> 1) & 7;
    int mh  = bid & 1;            // m = mh*8 + mi

    // Stage this block's weights (8 m x 80 floats = 2560 B) into LDS.
    __shared__ float ws[8 * 80];
    {
        const float4* src = (const float4*)(Wt + (b1 * 16 + mh * 8) * 80);
        for (int t = threadIdx.x; t < 160; t += 256)
            ((float4*)ws)[t] = src[t];
    }

    int c  = threadIdx.x & 15;    // x-chunk: x = 8c..8c+7
    int rr = threadIdx.x >> 4;    // row index
    int y  = b1 + (rr << 3);
    int x0 = c << 3;

    const float* xn = x + (size_t)n * (H * H);

    // in[dy][k] = coded[n, y+dy-1, x0+k-1] (zero padded)
    float in[3][10];
#pragma unroll
    for (int dy = 0; dy < 3; ++dy) {
        int ry = y + dy - 1;
        if (ry >= 0 && ry < H) {
            const float* row = xn + ry * H + x0;
            float4 a = *(const float4*)(row);
            float4 b = *(const float4*)(row + 4);
            in[dy][1] = a.x; in[dy][2] = a.y; in[dy][3] = a.z; in[dy][4] = a.w;
            in[dy][5] = b.x; in[dy][6] = b.y; in[dy][7] = b.z; in[dy][8] = b.w;
            in[dy][0] = (x0 > 0)     ? row[-1] : 0.0f;
            in[dy][9] = (x0 + 8 < H) ? row[8]  : 0.0f;
        } else {
#pragma unroll
            for (int k = 0; k < 10; ++k) in[dy][k] = 0.0f;
        }
    }

    __syncthreads();

    int odd = c & 1;
    // Pair base: lanes (2k,2k+1) cover x [16k, 16k+16)
    float* outbase = out + ((size_t)(n * SUB + mh * 8)) * (H * H)
                   + y * H + ((c >> 1) << 4);

#pragma unroll
    for (int mi = 0; mi < 8; ++mi) {
        const float* wp = ws + mi * 80;    // wave-uniform -> ds_read broadcast
        float acc[8];
#pragma unroll
        for (int j = 0; j < 8; ++j) acc[j] = wp[72 + j];   // bias
#pragma unroll
        for (int dy = 0; dy < 3; ++dy) {
#pragma unroll
            for (int dj = 0; dj < 3; ++dj) {
#pragma unroll
                for (int j = 0; j < 8; ++j) {
                    acc[j] = fmaf(in[dy][j + dj], wp[j * 9 + dy * 3 + dj], acc[j]);
                }
            }
        }
        // Pair-swap so each store instruction writes 32B contiguous per lane pair:
        // even lane: s1 = own acc[0..3] @ +0,  s2 = odd's acc[0..3] @ +8
        // odd  lane: s1 = even's acc[4..7] @ +4, s2 = own acc[4..7] @ +12
        float ex0 = __shfl_xor(odd ? acc[0] : acc[4], 1);
        float ex1 = __shfl_xor(odd ? acc[1] : acc[5], 1);
        float ex2 = __shfl_xor(odd ? acc[2] : acc[6], 1);
        float ex3 = __shfl_xor(odd ? acc[3] : acc[7], 1);
        float4 s1, s2;
        if (odd) {
            s1 = make_float4(ex0, ex1, ex2, ex3);
            s2 = make_float4(acc[4], acc[5], acc[6], acc[7]);
        } else {
            s1 = make_float4(acc[0], acc[1], acc[2], acc[3]);
            s2 = make_float4(ex0, ex1, ex2, ex3);
        }
        float* op = outbase + (size_t)mi * (H * H);
        *(float4*)(op + (odd << 2))     = s1;
        *(float4*)(op + 8 + (odd << 2)) = s2;
    }
}

extern "C" void kernel_launch(void* const* d_in, const int* in_sizes, int n_in,
                              void* d_out, int out_size, void* d_ws, size_t ws_size,
                              hipStream_t stream) {
    const float* coded  = (const float*)d_in[0];
    const float* weight = (const float*)d_in[1];
    const float* bias   = (const float*)d_in[2];
    float* out = (float*)d_out;
    float* Wt  = (float*)d_ws;   // 8*16*80*4 = 40960 bytes

    wprep_kernel<<<4, 256, 0, stream>>>(weight, bias, Wt);
    shiftconv_kernel<<<N_BATCH * 8 * 2, 256, 0, stream>>>(coded, Wt, out);
}

// Round 3
// 151.246 us; speedup vs baseline: 1.5244x; 1.3211x over previous
//
#include <hip/hip_runtime.h>

// ShiftVarConv2D: out[n,m,y,x] = sum_{di,dj} coded[n,y+di-1,x+dj-1] *
//                 W[(y%8)*8+(x%8), m, di*3+dj] + bias[g*16+m]
// N=128, H=128, SUB=16 out channels, 3x3 window, weights vary with (y%8,x%8).

#define H 128
#define N_BATCH 128
#define SUB 16

// Transpose weights+bias into [b1][m][80] : 72 weights (b2*9+i) + 8 bias (b2).
__global__ void wprep_kernel(const float* __restrict__ w,
                             const float* __restrict__ bias,
                             float* __restrict__ Wt) {
    int t = blockIdx.x * blockDim.x + threadIdx.x;   // 0..1023
    if (t >= 8 * 16 * 8) return;
    int b1 = t >> 7;          // 0..7
    int m  = (t >> 3) & 15;   // 0..15
    int j  = t & 7;           // 0..7  (= b2)
    int oc = (b1 * 8 + j) * 16 + m;
    float* dst = Wt + (b1 * 16 + m) * 80;
#pragma unroll
    for (int i = 0; i < 9; ++i) dst[j * 9 + i] = w[oc * 9 + i];
    dst[72 + j] = bias[oc];
}

// grid = 4096 blocks (n:128, b1:8, rh:2, mh:2), XCD-swizzled: low 3 bits = n&7.
// block = 256 threads: c = t&31 -> x0 = 4c (one float4 of output per m),
// r8 = t>>5 -> row y = b1 + 64*rh + 8*r8. Stores are wave-contiguous:
// 32 lanes x 16B = 512B per half-wave, every 64B line written by one instr.
__global__ __launch_bounds__(256, 8) void shiftconv_kernel(
        const float* __restrict__ x,
        const float* __restrict__ Wt,
        float* __restrict__ out) {
    int bid = blockIdx.x;
    int nlo = bid & 7;            // XCD-swizzle: same n -> same XCD
    int q   = bid >> 3;
    int mh  = q & 1;
    int rh  = (q >> 1) & 1;
    int b1  = (q >> 2) & 7;
    int n   = ((q >> 5) << 3) | nlo;

    // Stage this block's weights (8 m x 80 floats = 2560 B) into LDS.
    __shared__ float ws[8 * 80];
    {
        int t = threadIdx.x;
        if (t < 160)
            ((float4*)ws)[t] = ((const float4*)(Wt + (b1 * 16 + mh * 8) * 80))[t];
    }

    int c  = threadIdx.x & 31;    // x0 = 4c
    int r8 = threadIdx.x >> 5;    // 0..7
    int y  = b1 + (rh << 6) + (r8 << 3);
    int x0 = c << 2;
    int h  = c & 1;               // x0 % 8 == 4h -> b2 = 4h + j

    const float* xn = x + (size_t)n * (H * H);

    // in[dy][k] = coded[n, y+dy-1, x0+k-1] (zero padded), k in [0,6)
    float in[3][6];
#pragma unroll
    for (int dy = 0; dy < 3; ++dy) {
        int ry = y + dy - 1;
        if (ry >= 0 && ry < H) {
            const float* row = xn + ry * H + x0;
            float4 a = *(const float4*)(row);
            in[dy][1] = a.x; in[dy][2] = a.y; in[dy][3] = a.z; in[dy][4] = a.w;
            in[dy][0] = (x0 > 0)     ? row[-1] : 0.0f;
            in[dy][5] = (x0 + 4 < H) ? row[4]  : 0.0f;
        } else {
#pragma unroll
            for (int k = 0; k < 6; ++k) in[dy][k] = 0.0f;
        }
    }

    __syncthreads();

    float* outbase = out + ((size_t)(n * SUB + mh * 8)) * (H * H) + y * H + x0;

#pragma unroll
    for (int mi = 0; mi < 8; ++mi) {
        const float* wb  = ws + mi * 80;
        const float* wpp = wb + h * 36;        // weights for this b2-half
        float acc[4];
#pragma unroll
        for (int j = 0; j < 4; ++j) acc[j] = wb[72 + 4 * h + j];   // bias
#pragma unroll
        for (int dy = 0; dy < 3; ++dy) {
#pragma unroll
            for (int dj = 0; dj < 3; ++dj) {
#pragma unroll
                for (int j = 0; j < 4; ++j) {
                    acc[j] = fmaf(in[dy][j + dj], wpp[j * 9 + dy * 3 + dj], acc[j]);
                }
            }
        }
        *(float4*)(outbase + (size_t)mi * (H * H)) =
            make_float4(acc[0], acc[1], acc[2], acc[3]);
    }
}

extern "C" void kernel_launch(void* const* d_in, const int* in_sizes, int n_in,
                              void* d_out, int out_size, void* d_ws, size_t ws_size,
                              hipStream_t stream) {
    const float* coded  = (const float*)d_in[0];
    const float* weight = (const float*)d_in[1];
    const float* bias   = (const float*)d_in[2];
    float* out = (float*)d_out;
    float* Wt  = (float*)d_ws;   // 8*16*80*4 = 40960 bytes

    wprep_kernel<<<4, 256, 0, stream>>>(weight, bias, Wt);
    shiftconv_kernel<<<N_BATCH * 8 * 2 * 2, 256, 0, stream>>>(coded, Wt, out);
}